// Round 1
// 489.126 us; speedup vs baseline: 1.2530x; 1.2530x over previous
//
#include <hip/hip_runtime.h>
#include <cstdint>

#define BH  16
#define SEQ 2048
#define DIM 64
#define OUT_ELEMS (BH*SEQ*DIM)   // 2097152 floats; attn follows at this offset

typedef float f32x4 __attribute__((ext_vector_type(4)));
typedef float f32x2 __attribute__((ext_vector_type(2)));
typedef short bf16x8 __attribute__((ext_vector_type(8)));
typedef unsigned short u16;
typedef unsigned short u16x4 __attribute__((ext_vector_type(4)));

#define MFMA16 __builtin_amdgcn_mfma_f32_16x16x32_bf16

// ---- old-kernel LDS partition (fallback path) ----
#define SROW      2052
#define VTM_OFF   (16*SROW)
#define TL_OFF    (VTM_OFF + 4352)
#define QS_OFF    (TL_OFF + 1024)
#define RED_OFF   (QS_OFF + 1024)
#define LDS_FLOATS (RED_OFF + 160)
#define LDS_BYTES  (LDS_FLOATS*4)

// ---- new-kernel LDS partition ----
#define M_OFF2    (16*SROW)             // M fp32[64][64]
#define TL_OFF2   (M_OFF2 + 4096)       // T fp32[16][64]
#define QS_OFF2   (TL_OFF2 + 1024)      // q fp32[16][64]
#define RED_OFF2  (QS_OFF2 + 1024)      // red[16][16] + mrow[16] + linv[16]
#define LDS2_FLOATS (RED_OFF2 + 288)
#define LDS2_BYTES  (LDS2_FLOATS*4)     // 157056 B -> 1 block/CU, 16 waves

__device__ __forceinline__ u16 f2bf(float x){            // RNE f32->bf16
  uint32_t u = __float_as_uint(x);
  return (u16)((u + 0x7fffu + ((u>>16)&1u)) >> 16);
}
__device__ __forceinline__ void split8(f32x4 a, f32x4 b, bf16x8& hi, bf16x8& lo){
  float v[8] = {a.x,a.y,a.z,a.w,b.x,b.y,b.z,b.w};
  #pragma unroll
  for (int i=0;i<8;i++){
    uint32_t u  = __float_as_uint(v[i]);
    uint32_t hb = u & 0xffff0000u;
    hi[i] = (short)(hb>>16);
    lo[i] = (short)f2bf(v[i] - __uint_as_float(hb));
  }
}
__device__ __forceinline__ bf16x8 pack8(f32x4 a, f32x4 b){
  bf16x8 r;
  r[0]=(short)f2bf(a.x); r[1]=(short)f2bf(a.y); r[2]=(short)f2bf(a.z); r[3]=(short)f2bf(a.w);
  r[4]=(short)f2bf(b.x); r[5]=(short)f2bf(b.y); r[6]=(short)f2bf(b.z); r[7]=(short)f2bf(b.w);
  return r;
}

// ---------------- Kernel A1: partial M = k^T q (per batch, per 128-row chunk) ------
__global__ __launch_bounds__(256) void kA1(const float* __restrict__ kk,
                                           const float* __restrict__ qq,
                                           float* __restrict__ part){
  __shared__ __align__(16) float kl[64][68];
  __shared__ __align__(16) float ql[64][68];
  const int b   = blockIdx.y;
  const int ch  = blockIdx.x;
  const int tid = threadIdx.x;
  const int j     = tid & 63;
  const int ibase = (tid >> 6) * 16;   // wave-uniform
  const int lrow  = tid >> 2;
  const int lcol  = (tid & 3) * 16;
  const float* kb = kk + (size_t)b*SEQ*DIM;
  const float* qb = qq + (size_t)b*SEQ*DIM;
  float acc[16];
  #pragma unroll
  for (int i=0;i<16;i++) acc[i]=0.f;
  for (int sub=0; sub<2; ++sub){
    const int l0 = ch*128 + sub*64;
    const f32x4* ks = (const f32x4*)(kb + (size_t)(l0+lrow)*DIM + lcol);
    const f32x4* qs = (const f32x4*)(qb + (size_t)(l0+lrow)*DIM + lcol);
    f32x4 kv[4], qv[4];
    #pragma unroll
    for (int i=0;i<4;i++){ kv[i]=ks[i]; qv[i]=qs[i]; }
    __syncthreads();
    #pragma unroll
    for (int i=0;i<4;i++){
      *(f32x4*)&kl[lrow][lcol+4*i] = kv[i];
      *(f32x4*)&ql[lrow][lcol+4*i] = qv[i];
    }
    __syncthreads();
    for (int t=0; t<64; ++t){
      const float qv1 = ql[t][j];
      const f32x4 k0 = *(const f32x4*)&kl[t][ibase];
      const f32x4 k1 = *(const f32x4*)&kl[t][ibase+4];
      const f32x4 k2 = *(const f32x4*)&kl[t][ibase+8];
      const f32x4 k3 = *(const f32x4*)&kl[t][ibase+12];
      acc[0]+=k0.x*qv1; acc[1]+=k0.y*qv1; acc[2]+=k0.z*qv1; acc[3]+=k0.w*qv1;
      acc[4]+=k1.x*qv1; acc[5]+=k1.y*qv1; acc[6]+=k1.z*qv1; acc[7]+=k1.w*qv1;
      acc[8]+=k2.x*qv1; acc[9]+=k2.y*qv1; acc[10]+=k2.z*qv1; acc[11]+=k2.w*qv1;
      acc[12]+=k3.x*qv1; acc[13]+=k3.y*qv1; acc[14]+=k3.z*qv1; acc[15]+=k3.w*qv1;
    }
  }
  float* pp = part + (size_t)(b*16+ch)*4096;
  #pragma unroll
  for (int ii=0; ii<16; ++ii)
    pp[(ibase+ii)*64 + j] = acc[ii];
}

// ---------------- Kernel A2: reduce partials, fold 1/temper^2 ----------------------
__global__ __launch_bounds__(256) void kA2(const float* __restrict__ part,
                                           float* __restrict__ M){
  const int idx = blockIdx.x*256 + threadIdx.x;
  const int b = idx >> 12, o = idx & 4095;
  float s = 0.f;
  #pragma unroll
  for (int ch=0; ch<16; ++ch)
    s += part[(size_t)(b*16+ch)*4096 + o];
  M[(size_t)b*4096 + o] = s * (1.0f/64.0f);
}

// ---------------- Kernel P: precondition operands (hi/lo pos planes, vT bf16) -----
__global__ __launch_bounds__(512) void kP(const float* __restrict__ pos,
                                          const float* __restrict__ v,
                                          u16* __restrict__ posH,
                                          u16* __restrict__ posL,
                                          u16* __restrict__ vTg){
  __shared__ u16 vt[64][136];
  const int b   = blockIdx.y;
  const int ch  = blockIdx.x;            // 128-row chunk
  const int tid = threadIdx.x;
  // ---- pos hi/lo planes for 128 rows (identical split8 math as old kernel) ----
  {
    const f32x4* pb = (const f32x4*)(pos + (size_t)b*SEQ*DIM + (size_t)ch*128*DIM);
    u16* pH = posH + (size_t)b*SEQ*DIM + (size_t)ch*128*DIM;
    u16* pL = posL + (size_t)b*SEQ*DIM + (size_t)ch*128*DIM;
    #pragma unroll
    for (int i=0;i<4;i++){
      const int idx = i*512 + tid;
      const f32x4 x = pb[idx];
      const float xs[4] = {x.x,x.y,x.z,x.w};
      u16x4 h, l;
      #pragma unroll
      for (int jj=0;jj<4;jj++){
        uint32_t u  = __float_as_uint(xs[jj]);
        uint32_t hb = u & 0xffff0000u;
        h[jj] = (u16)(hb>>16);
        l[jj] = f2bf(xs[jj] - __uint_as_float(hb));
      }
      *(u16x4*)&pH[idx*4] = h;
      *(u16x4*)&pL[idx*4] = l;
    }
  }
  // ---- v[ch*128..+128)[64] -> vt[d][c] bf16 (register transpose, as old kernel) --
  {
    const float* vb = v + (size_t)b*SEQ*DIM;
    const int c4 = (tid & 31)*4;
    const int d4 = (tid >> 5)*4;
    const int cg = ch*128 + c4;
    f32x4 r0v = *(const f32x4*)(vb + (size_t)(cg  )*DIM + d4);
    f32x4 r1v = *(const f32x4*)(vb + (size_t)(cg+1)*DIM + d4);
    f32x4 r2v = *(const f32x4*)(vb + (size_t)(cg+2)*DIM + d4);
    f32x4 r3v = *(const f32x4*)(vb + (size_t)(cg+3)*DIM + d4);
    const float rr[4][4] = {{r0v.x,r1v.x,r2v.x,r3v.x},
                            {r0v.y,r1v.y,r2v.y,r3v.y},
                            {r0v.z,r1v.z,r2v.z,r3v.z},
                            {r0v.w,r1v.w,r2v.w,r3v.w}};
    #pragma unroll
    for (int dd=0; dd<4; ++dd){
      u16x4 pk;
      pk[0]=f2bf(rr[dd][0]); pk[1]=f2bf(rr[dd][1]);
      pk[2]=f2bf(rr[dd][2]); pk[3]=f2bf(rr[dd][3]);
      *(u16x4*)&vt[d4+dd][c4] = pk;
    }
  }
  __syncthreads();
  // ---- coalesced copy-out: vTg[b][d][k], k contiguous ----
  {
    const int d    = tid >> 3;           // 0..63
    const int roff = (tid & 7)*16;       // 0..112
    u16* dst = vTg + (size_t)b*DIM*SEQ + (size_t)d*SEQ + ch*128 + roff;
    const u16* src = &vt[d][roff];
    #pragma unroll
    for (int kq=0; kq<4; ++kq)
      *(u16x4*)(dst + kq*4) = *(const u16x4*)(src + kq*4);
  }
}

// ---------------- Kernel B v2: 1024-thread persistent MFMA kernel -----------------
// grid 256 (1 block/CU), 16 waves (4/SIMD), task = 16 q-rows, 8 tasks/block.
// PV and logits B-operands come straight from L2-resident bf16 planes: no LDS
// staging, no barriers in the PV loop. 9 barriers/task (was ~40).
__global__ __launch_bounds__(1024,4) void kB(const float* __restrict__ q,
                                             const float* __restrict__ M,
                                             const u16* __restrict__ posH,
                                             const u16* __restrict__ posL,
                                             const u16* __restrict__ vTg,
                                             float* __restrict__ outp,
                                             float* __restrict__ attn){
  extern __shared__ __align__(16) float smem[];
  float* S    = smem;                        // [16][SROW] logits->exp; Pfrag overlay
  float* Ml   = smem + M_OFF2;               // M fp32[64][64]
  float* Tl   = smem + TL_OFF2;              // T fp32[16][64]
  float* qs   = smem + QS_OFF2;              // q fp32[16][64]
  float* red  = smem + RED_OFF2;             // [16][16]
  float* mrow = red + 256;                   // [16]
  float* linv = mrow + 16;                   // [16]

  const int blk   = blockIdx.x;
  const int xcd   = blk & 7;
  const int slot  = blk >> 3;                // 0..31
  const int b     = xcd*2 + (slot & 1);
  const int bslot = slot >> 1;               // 0..15
  const int tid   = threadIdx.x;
  const int lane  = tid & 63;
  const int w     = tid >> 6;                // 0..15
  const int quad  = lane >> 4;
  const int l16   = lane & 15;

  const float* qb  = q    + (size_t)b*SEQ*DIM;
  const float* Mb  = M    + (size_t)b*4096;
  const u16*   pHb = posH + (size_t)b*SEQ*DIM;
  const u16*   pLb = posL + (size_t)b*SEQ*DIM;
  const u16*   vTb = vTg  + (size_t)b*SEQ*DIM;

  // stage M once per block (constant across tasks); visible after t=0 barrier
  ((f32x4*)Ml)[tid] = ((const f32x4*)Mb)[tid];

  for (int t = 0; t < 8; ++t){
    const int r0 = (bslot*8 + t) * 16;
    // stage q rows for THIS task (qs only read post-barrier; no hazard with prev)
    if (tid < 256)
      ((f32x4*)qs)[tid] = ((const f32x4*)(qb + (size_t)r0*DIM))[tid];
    __syncthreads();                          // prev task S reads done; M/qs visible

    // ---- T[16][64] = qs * M : wave w -> row w, 4-way d-split + shuffle reduce ----
    {
      const int cg = l16;                     // col group (4 floats)
      const int dh = quad;                    // d-quarter
      f32x4 a = {0.f,0.f,0.f,0.f};
      #pragma unroll
      for (int dd=0; dd<16; ++dd){
        const int d = dh*16 + dd;
        const float qd = qs[w*64 + d];
        const f32x4 mr = *(const f32x4*)&Ml[d*64 + cg*4];
        a.x += qd*mr.x; a.y += qd*mr.y; a.z += qd*mr.z; a.w += qd*mr.w;
      }
      a.x += __shfl_xor(a.x,16,64); a.y += __shfl_xor(a.y,16,64);
      a.z += __shfl_xor(a.z,16,64); a.w += __shfl_xor(a.w,16,64);
      a.x += __shfl_xor(a.x,32,64); a.y += __shfl_xor(a.y,32,64);
      a.z += __shfl_xor(a.z,32,64); a.w += __shfl_xor(a.w,32,64);
      if (lane < 16) *(f32x4*)&Tl[w*64 + cg*4] = a;
    }
    __syncthreads();

    // ---- A-frags (T hi/lo) for both k-halves ----
    bf16x8 Ah[2], Al[2];
    #pragma unroll
    for (int h=0; h<2; ++h){
      const float* ts = &Tl[l16*64 + h*32 + quad*8];
      split8(*(const f32x4*)ts, *(const f32x4*)(ts+4), Ah[h], Al[h]);
    }

    // ---- logits: wave w covers c in [w*128, w*128+128), B-frags from global ----
    #pragma unroll 2
    for (int tt=0; tt<8; ++tt){
      const int c0 = w*128 + tt*16;
      const size_t pbase = (size_t)(c0 + l16)*DIM + quad*8;
      const bf16x8 Bh0 = *(const bf16x8*)&pHb[pbase];
      const bf16x8 Bl0 = *(const bf16x8*)&pLb[pbase];
      const bf16x8 Bh1 = *(const bf16x8*)&pHb[pbase + 32];
      const bf16x8 Bl1 = *(const bf16x8*)&pLb[pbase + 32];
      f32x4 acc = {0.f,0.f,0.f,0.f};
      acc = MFMA16(Ah[0], Bh0, acc, 0,0,0);
      acc = MFMA16(Al[0], Bh0, acc, 0,0,0);
      acc = MFMA16(Ah[0], Bl0, acc, 0,0,0);
      acc = MFMA16(Ah[1], Bh1, acc, 0,0,0);
      acc = MFMA16(Al[1], Bh1, acc, 0,0,0);
      acc = MFMA16(Ah[1], Bl1, acc, 0,0,0);
      #pragma unroll
      for (int i=0;i<4;i++)
        S[(quad*4+i)*SROW + c0 + l16] = acc[i];
    }
    __syncthreads();

    // ---- row max (r = tid&15, seg = tid>>4, 32 cols/seg) ----
    {
      const int r = tid & 15, seg = tid >> 4;
      const f32x4* sr = (const f32x4*)&S[r*SROW + seg*32];
      float m = -3.0e38f;
      #pragma unroll
      for (int i=0;i<8;i++){
        const f32x4 x = sr[i];
        m = fmaxf(m, fmaxf(fmaxf(x.x,x.y), fmaxf(x.z,x.w)));
      }
      m = fmaxf(m, __shfl_xor(m, 16, 64));
      m = fmaxf(m, __shfl_xor(m, 32, 64));
      if (lane < 16) red[w*16 + lane] = m;
    }
    __syncthreads();
    if (tid < 16){
      float m = red[tid];
      #pragma unroll
      for (int w2=1; w2<16; ++w2) m = fmaxf(m, red[w2*16 + tid]);
      mrow[tid] = m;
    }
    __syncthreads();

    // ---- exp in place + row sums ----
    {
      const int r = tid & 15, seg = tid >> 4;
      const float mr = mrow[r];
      f32x4* sr = (f32x4*)&S[r*SROW + seg*32];
      float s = 0.f;
      #pragma unroll
      for (int i=0;i<8;i++){
        f32x4 x = sr[i];
        x.x = __expf(x.x - mr); x.y = __expf(x.y - mr);
        x.z = __expf(x.z - mr); x.w = __expf(x.w - mr);
        sr[i] = x;
        s += x.x + x.y + x.z + x.w;
      }
      s += __shfl_xor(s, 16, 64);
      s += __shfl_xor(s, 32, 64);
      if (lane < 16) red[w*16 + lane] = s;
    }
    __syncthreads();
    if (tid < 16){
      float s = red[tid];
      #pragma unroll
      for (int w2=1; w2<16; ++w2) s += red[w2*16 + tid];
      linv[tid] = 1.0f / s;
    }
    __syncthreads();

    // ---- attn = e * linv : wave w -> row w, coalesced nontemporal b128 ----
    {
      const float li = linv[w];
      float* ab = attn + ((size_t)b*SEQ + r0 + w)*(size_t)SEQ;
      const float* srow = &S[w*SROW];
      #pragma unroll
      for (int j=0;j<8;++j){
        const int c = lane*4 + 256*j;
        f32x4 val = *(const f32x4*)(srow + c);
        val.x *= li; val.y *= li; val.z *= li; val.w *= li;
        __builtin_nontemporal_store(val, (f32x4*)(ab + c));
      }
    }

    // ---- PV: wave (kch = w&7, dh = w>>3); B from global vT bf16; NO barriers ----
    f32x4 pacc0 = {0.f,0.f,0.f,0.f}, pacc1 = {0.f,0.f,0.f,0.f};
    const int kch = w & 7;                    // 8 k-chunks of 256
    const int dh  = w >> 3;                   // 2 d-halves (2 n-tiles each)
    #pragma unroll 2
    for (int s8=0; s8<8; ++s8){
      const int k0 = kch*256 + s8*32;
      const float* es = &S[l16*SROW + k0 + quad*8];
      const bf16x8 Af = pack8(*(const f32x4*)es, *(const f32x4*)(es+4));
      const bf16x8 B0 = *(const bf16x8*)&vTb[(size_t)(dh*32      + l16)*SEQ + k0 + quad*8];
      const bf16x8 B1 = *(const bf16x8*)&vTb[(size_t)(dh*32 + 16 + l16)*SEQ + k0 + quad*8];
      pacc0 = MFMA16(Af, B0, pacc0, 0,0,0);
      pacc1 = MFMA16(Af, B1, pacc1, 0,0,0);
    }
    __syncthreads();                          // all S reads (attn + PV) done
    {   // Pfrag overlay into S: slot kch holds [16][64]
      float* Pf = S + kch*1024;
      #pragma unroll
      for (int i=0;i<4;i++){
        Pf[(quad*4+i)*64 + dh*32      + l16] = pacc0[i];
        Pf[(quad*4+i)*64 + dh*32 + 16 + l16] = pacc1[i];
      }
    }
    __syncthreads();
    {   // reduce 8 k-chunk partials, scale, write out (1 float/thread)
      const int m = tid >> 6;
      float s = 0.f;
      #pragma unroll
      for (int kk=0; kk<8; ++kk)
        s += S[kk*1024 + tid];
      outp[((size_t)b*SEQ + r0 + m)*DIM + (tid & 63)] = s * linv[m];
    }
  }
}

// ---------------- Kernel B v1 (fallback when workspace is too small) --------------
__global__ __launch_bounds__(512,2) void kB_old(const float* __restrict__ q,
                                                const float* __restrict__ pos,
                                                const float* __restrict__ v,
                                                const float* __restrict__ M,
                                                float* __restrict__ outp,
                                                float* __restrict__ attn){
  extern __shared__ __align__(16) float smem[];
  float* S    = smem;
  float* VTM  = smem + VTM_OFF;
  u16*   vT   = (u16*)VTM;
  float* Tl   = smem + TL_OFF;
  float* qs   = smem + QS_OFF;
  float* red  = smem + RED_OFF;
  float* mrow = red + 128;
  float* linv = mrow + 16;

  const int blk   = blockIdx.x;
  const int xcd   = blk & 7;
  const int slot  = blk >> 3;
  const int b     = xcd*2 + (slot & 1);
  const int bslot = slot >> 1;
  const int tid   = threadIdx.x;
  const int lane  = tid & 63;
  const int w     = tid >> 6;
  const int quad  = lane >> 4;
  const int l16   = lane & 15;

  const float* pb = pos + (size_t)b*SEQ*DIM;
  const float* vb = v   + (size_t)b*SEQ*DIM;
  const float* qb = q   + (size_t)b*SEQ*DIM;
  const float* Mb = M   + (size_t)b*4096;

  for (int t = 0; t < 8; ++t){
    const int r0 = (bslot*8 + t) * 16;
    __syncthreads();
    {
      const f32x4* Mg = (const f32x4*)Mb;
      f32x4* Md = (f32x4*)VTM;
      Md[tid]     = Mg[tid];
      Md[tid+512] = Mg[tid+512];
      if (tid < 256)
        ((f32x4*)qs)[tid] = ((const f32x4*)(qb + (size_t)r0*DIM))[tid];
    }
    __syncthreads();
    {
      const int r = tid >> 5;
      const int e = tid & 31;
      float a0 = 0.f, a1 = 0.f;
      #pragma unroll 8
      for (int d=0; d<64; ++d){
        const float qd = qs[r*64 + d];
        a0 += qd * VTM[d*64 + e];
        a1 += qd * VTM[d*64 + e + 32];
      }
      Tl[r*64 + e]      = a0;
      Tl[r*64 + e + 32] = a1;
    }
    __syncthreads();
    bf16x8 Ah[2], Al[2];
    #pragma unroll
    for (int h=0; h<2; ++h){
      const float* ts = &Tl[l16*64 + h*32 + quad*8];
      split8(*(const f32x4*)ts, *(const f32x4*)(ts+4), Ah[h], Al[h]);
    }
    #pragma unroll 2
    for (int tt=0; tt<16; ++tt){
      const int c0 = w*256 + tt*16;
      const float* pr = pb + (size_t)(c0 + l16)*DIM + quad*8;
      f32x4 p0 = *(const f32x4*)pr;
      f32x4 p1 = *(const f32x4*)(pr+4);
      f32x4 p2 = *(const f32x4*)(pr+32);
      f32x4 p3 = *(const f32x4*)(pr+36);
      bf16x8 Bh0, Bl0, Bh1, Bl1;
      split8(p0, p1, Bh0, Bl0);
      split8(p2, p3, Bh1, Bl1);
      f32x4 acc = {0.f,0.f,0.f,0.f};
      acc = MFMA16(Ah[0], Bh0, acc, 0,0,0);
      acc = MFMA16(Al[0], Bh0, acc, 0,0,0);
      acc = MFMA16(Ah[0], Bl0, acc, 0,0,0);
      acc = MFMA16(Ah[1], Bh1, acc, 0,0,0);
      acc = MFMA16(Al[1], Bh1, acc, 0,0,0);
      acc = MFMA16(Ah[1], Bl1, acc, 0,0,0);
      #pragma unroll
      for (int i=0;i<4;i++)
        S[(quad*4+i)*SROW + c0 + l16] = acc[i];
    }
    __syncthreads();
    {
      const int r = tid & 15, seg = tid >> 4;
      const f32x4* sr = (const f32x4*)&S[r*SROW + seg*64];
      float m = -3.0e38f;
      #pragma unroll
      for (int i=0;i<16;i++){
        const f32x4 x = sr[i];
        m = fmaxf(m, fmaxf(fmaxf(x.x,x.y), fmaxf(x.z,x.w)));
      }
      m = fmaxf(m, __shfl_xor(m, 16, 64));
      m = fmaxf(m, __shfl_xor(m, 32, 64));
      if (lane < 16) red[w*16 + lane] = m;
    }
    __syncthreads();
    if (tid < 16){
      float m = red[tid];
      #pragma unroll
      for (int w2=1; w2<8; ++w2) m = fmaxf(m, red[w2*16 + tid]);
      mrow[tid] = m;
    }
    __syncthreads();
    {
      const int r = tid & 15, seg = tid >> 4;
      const float mr = mrow[r];
      f32x4* sr = (f32x4*)&S[r*SROW + seg*64];
      float s = 0.f;
      #pragma unroll
      for (int i=0;i<16;i++){
        f32x4 x = sr[i];
        x.x = __expf(x.x - mr); x.y = __expf(x.y - mr);
        x.z = __expf(x.z - mr); x.w = __expf(x.w - mr);
        sr[i] = x;
        s += x.x + x.y + x.z + x.w;
      }
      s += __shfl_xor(s, 16, 64);
      s += __shfl_xor(s, 32, 64);
      if (lane < 16) red[w*16 + lane] = s;
    }
    __syncthreads();
    if (tid < 16){
      float s = red[tid];
      #pragma unroll
      for (int w2=1; w2<8; ++w2) s += red[w2*16 + tid];
      linv[tid] = 1.0f / s;
    }
    __syncthreads();
    {
      const int r  = tid >> 5;
      const int cq = (tid & 31) * 4;
      const float li = linv[r];
      float* ab = attn + ((size_t)b*SEQ + r0 + r)*(size_t)SEQ;
      const float* sr = &S[r*SROW];
      #pragma unroll
      for (int j=0;j<16;++j){
        const int c = cq + 128*j;
        f32x4 val = *(const f32x4*)(sr + c);
        val.x *= li; val.y *= li; val.z *= li; val.w *= li;
        __builtin_nontemporal_store(val, (f32x4*)(ab + c));
      }
    }
    f32x4 pacc0 = {0.f,0.f,0.f,0.f}, pacc1 = {0.f,0.f,0.f,0.f};
    const int kch   = w >> 1;
    const int npair = w & 1;
    for (int vt2=0; vt2<16; ++vt2){
      __syncthreads();
      {
        const int c4 = (tid & 31)*4;
        const int d4 = (tid >> 5)*4;
        const int cg = vt2*128 + c4;
        f32x4 r0v = *(const f32x4*)(vb + (size_t)(cg  )*DIM + d4);
        f32x4 r1v = *(const f32x4*)(vb + (size_t)(cg+1)*DIM + d4);
        f32x4 r2v = *(const f32x4*)(vb + (size_t)(cg+2)*DIM + d4);
        f32x4 r3v = *(const f32x4*)(vb + (size_t)(cg+3)*DIM + d4);
        const float rr[4][4] = {{r0v.x,r1v.x,r2v.x,r3v.x},
                                {r0v.y,r1v.y,r2v.y,r3v.y},
                                {r0v.z,r1v.z,r2v.z,r3v.z},
                                {r0v.w,r1v.w,r2v.w,r3v.w}};
        #pragma unroll
        for (int dd=0; dd<4; ++dd){
          u16x4 pk;
          pk[0]=f2bf(rr[dd][0]); pk[1]=f2bf(rr[dd][1]);
          pk[2]=f2bf(rr[dd][2]); pk[3]=f2bf(rr[dd][3]);
          *(u16x4*)&vT[(d4+dd)*136 + c4] = pk;
        }
      }
      __syncthreads();
      {
        const int cbase = kch*32;
        const float* es = &S[l16*SROW + vt2*128 + cbase + quad*8];
        const bf16x8 Af = pack8(*(const f32x4*)es, *(const f32x4*)(es+4));
        const int n0 = (npair*2)*16 + l16;
        const int n1 = n0 + 16;
        const bf16x8 B0 = *(const bf16x8*)&vT[n0*136 + cbase + quad*8];
        const bf16x8 B1 = *(const bf16x8*)&vT[n1*136 + cbase + quad*8];
        pacc0 = MFMA16(Af, B0, pacc0, 0,0,0);
        pacc1 = MFMA16(Af, B1, pacc1, 0,0,0);
      }
    }
    __syncthreads();
    {
      float* Pf = S;
      #pragma unroll
      for (int i=0;i<4;i++){
        Pf[(w*2+0)*256 + (quad*4+i)*16 + l16] = pacc0[i];
        Pf[(w*2+1)*256 + (quad*4+i)*16 + l16] = pacc1[i];
      }
      pacc0 = (f32x4){0.f,0.f,0.f,0.f};
      pacc1 = (f32x4){0.f,0.f,0.f,0.f};
    }
    __syncthreads();
    {
      const int o = tid*2;
      const int m = o >> 6;
      const int d = o & 63;
      const int nt = d >> 4;
      float s0 = 0.f, s1 = 0.f;
      #pragma unroll
      for (int kk=0; kk<4; ++kk){
        const int sl = (2*kk + (nt>>1))*2 + (nt&1);
        s0 += S[sl*256 + m*16 + (d&15)];
        s1 += S[sl*256 + m*16 + (d&15) + 1];
      }
      const float li = linv[m];
      f32x2 res; res.x = s0*li; res.y = s1*li;
      *(f32x2*)(outp + ((size_t)b*SEQ + r0 + m)*DIM + d) = res;
    }
  }
}

extern "C" void kernel_launch(void* const* d_in, const int* in_sizes, int n_in,
                              void* d_out, int out_size, void* d_ws, size_t ws_size,
                              hipStream_t stream){
  const float* q = (const float*)d_in[0];
  const float* k = (const float*)d_in[1];
  const float* v = (const float*)d_in[2];
  const float* p = (const float*)d_in[3];
  float* out  = (float*)d_out;
  float* attn = out + OUT_ELEMS;          // second tuple element
  float* M    = (float*)d_ws;             // 16*64*64 fp32 = 256 KB
  float* part = attn;                     // M-partials scratch; dead after kA2

  // ws layout: M (256 KB) | posH (4 MB) | posL (4 MB) | vT (4 MB)
  const size_t NEED = 262144 + 3ull*BH*SEQ*DIM*sizeof(u16);  // 12.85 MB

  hipFuncSetAttribute((const void*)kB,
                      hipFuncAttributeMaxDynamicSharedMemorySize, LDS2_BYTES);
  hipFuncSetAttribute((const void*)kB_old,
                      hipFuncAttributeMaxDynamicSharedMemorySize, LDS_BYTES);

  kA1<<<dim3(16,16), 256, 0, stream>>>(k, q, part);
  kA2<<<dim3(256),   256, 0, stream>>>(part, M);

  if (ws_size >= NEED){
    u16* posH = (u16*)((char*)d_ws + 262144);
    u16* posL = posH + (size_t)BH*SEQ*DIM;
    u16* vTg  = posL + (size_t)BH*SEQ*DIM;
    kP<<<dim3(16,16), 512, 0, stream>>>(p, v, posH, posL, vTg);
    kB<<<dim3(256), 1024, LDS2_BYTES, stream>>>(q, M, posH, posL, vTg, out, attn);
  } else {
    kB_old<<<dim3(256), 512, LDS_BYTES, stream>>>(q, p, v, M, out, attn);
  }
}